// Round 3
// 549.595 us; speedup vs baseline: 1.0095x; 1.0095x over previous
//
#include <hip/hip_runtime.h>
#include <hip/hip_bf16.h>
#include <math.h>

// ---------------------------------------------------------------------------
// LIF layer, round 13 (= R12 resubmit; R2 bench was an infra failure, kernel
// never ran): bf16x3 MFMA GEMM (R10 numerics, bitwise identical) +
// global_load_lds staging (R11's verified-correct mechanism) + banded scan +
// b-grouped exact repair.
//
// R11 post-mortem: K-interleaved (Ah,Al)x(Bh,Bl) computes DIAGONAL terms
// hh+ll only — cross terms hl+lh (the ~4e-3 Dekker correction) are never
// paired by the MFMA dot. absmax 1.0. No interleaving avoids the 3 K-passes.
// The gload_lds staging itself was correct by construction (LDS u16 offset
// tid*8 == R10's proven blocked layout; permutation in per-lane global addr).
//
// R12/R13: revert to 4-buffer 3-pass numerics (== R10 output bitwise), keep
// gload_lds(16B) staging for all 4 streams; drop the uint4 reg round-trip.
//
// Pipeline:
//   k1 zero    : 128 per-b worklist counters = 0
//   k2 split   : X,W f32 -> bf16 hi/lo (Dekker, exact residual)
//   k3 gemm    : 128x128x32 MFMA tiles, hh+hl+lh, gload_lds staging
//   k4 scan    : exact-f32 scan, spikes in place, tight chains -> worklist[b]
//   k5 repair  : per (b, group of 16 chains): exact Q=320-panel dots from
//                LDS-staged X (64t x 64k chunks), exact scan, overwrite.
// Fallback (ws too small): R8 fused exact kernel (known-passing).
// ---------------------------------------------------------------------------

typedef unsigned short u16;
typedef __attribute__((ext_vector_type(8))) short bf16x8;
typedef __attribute__((ext_vector_type(4))) float f32x4;

constexpr int T_STEPS = 64;
constexpr int BATCH   = 128;
constexpr int K_DIM   = 2048;
constexpr int N_DIM   = 2048;
constexpr int M_DIM   = T_STEPS * BATCH;      // 8192
constexpr int NCHAIN  = BATCH * N_DIM;        // 262144

constexpr float DECAY_F32 = (float)0.6065306597126334;
constexpr float BAND      = 5e-4f;

#define GLDS16(g, l) __builtin_amdgcn_global_load_lds(                       \
    (const __attribute__((address_space(1))) void*)(g),                      \
    (__attribute__((address_space(3))) void*)(l), 16, 0, 0)

// ---------------------------------------------------------------------------
__global__ void zero_counters(unsigned int* p) {
    if (threadIdx.x < 128) p[threadIdx.x] = 0u;
}

// ---------------------------------------------------------------------------
// k2: Dekker split f32 -> bf16 hi/lo, 4 elems/thread. (R10, verbatim)
// ---------------------------------------------------------------------------
__global__ __launch_bounds__(256)
void split_bf16(const float* __restrict__ X, const float* __restrict__ W,
                u16* __restrict__ Ah, u16* __restrict__ Al,
                u16* __restrict__ Wh, u16* __restrict__ Wl) {
    constexpr int NA4 = (M_DIM * K_DIM) / 4;
    constexpr int NW4 = (N_DIM * K_DIM) / 4;
    const int i = blockIdx.x * 256 + threadIdx.x;
    const float* src; u16* dh; u16* dl; int base;
    if (i < NA4)            { src = X; dh = Ah; dl = Al; base = i; }
    else if (i < NA4 + NW4) { src = W; dh = Wh; dl = Wl; base = i - NA4; }
    else return;

    const float4 v = *(const float4*)(src + (size_t)base * 4);
    const float f[4] = {v.x, v.y, v.z, v.w};
    unsigned int hp[2], lp[2];
#pragma unroll
    for (int q = 0; q < 4; q += 2) {
        u16 hh[2], ll[2];
#pragma unroll
        for (int e = 0; e < 2; e++) {
            __hip_bfloat16 hb = __float2bfloat16(f[q + e]);
            const float hf = __bfloat162float(hb);
            __hip_bfloat16 lb = __float2bfloat16(f[q + e] - hf);
            hh[e] = *(u16*)&hb;
            ll[e] = *(u16*)&lb;
        }
        hp[q >> 1] = (unsigned int)hh[0] | ((unsigned int)hh[1] << 16);
        lp[q >> 1] = (unsigned int)ll[0] | ((unsigned int)ll[1] << 16);
    }
    *(uint2*)(dh + (size_t)base * 4) = make_uint2(hp[0], hp[1]);
    *(uint2*)(dl + (size_t)base * 4) = make_uint2(lp[0], lp[1]);
}

// ---------------------------------------------------------------------------
// k3: bf16x3 MFMA GEMM (hh + hl + lh). 128x128 tile, BK=32, 4 waves 2x2.
// Staging via global_load_lds width=16: LDS blocked layout is linear in
// entry index c (c = tid for region 0, tid+256 for region 1), so the HW's
// wave-uniform-base + lane*16B write lands each lane's 16B at u16 offset
// tid*8 — exactly the R10 layout; the permutation lives in the per-lane
// GLOBAL address (m97 pattern). ds_read side unchanged from R10.
// ---------------------------------------------------------------------------
__global__ __launch_bounds__(256, 3)
void gemm_bf16x3(const u16* __restrict__ Ah, const u16* __restrict__ Al,
                 const u16* __restrict__ Bh, const u16* __restrict__ Bl,
                 const float* __restrict__ bias, float* __restrict__ C) {
    __shared__ __align__(16) u16 sAh[4096], sAl[4096], sBh[4096], sBl[4096];

    const int tid  = threadIdx.x;
    const int m0   = blockIdx.y * 128;
    const int n0   = blockIdx.x * 128;
    const int lane = tid & 63;
    const int wave = tid >> 6;
    const int wm   = wave >> 1;
    const int wn   = wave & 1;

    const int c0 = tid, c1 = tid + 256;
#define OFFA(c) ((size_t)(m0 + ((c) >> 6) * 16 + ((c) & 15)) * K_DIM + (((c) >> 4) & 3) * 8)
#define OFFB(c) ((size_t)(n0 + ((c) >> 6) * 16 + ((c) & 15)) * K_DIM + (((c) >> 4) & 3) * 8)
    const size_t a0 = OFFA(c0), a1 = OFFA(c1);
    const size_t b0 = OFFB(c0), b1 = OFFB(c1);
#undef OFFA
#undef OFFB

    // wave-uniform LDS dest bases (HW adds lane*16B); u16 offset tid*8.
    u16* lAh0 = sAh + wave * 512;  u16* lAh1 = sAh + 2048 + wave * 512;
    u16* lAl0 = sAl + wave * 512;  u16* lAl1 = sAl + 2048 + wave * 512;
    u16* lBh0 = sBh + wave * 512;  u16* lBh1 = sBh + 2048 + wave * 512;
    u16* lBl0 = sBl + wave * 512;  u16* lBl1 = sBl + 2048 + wave * 512;

    f32x4 acc[4][4];
#pragma unroll
    for (int i = 0; i < 4; i++)
#pragma unroll
        for (int j = 0; j < 4; j++) acc[i][j] = (f32x4){0.f, 0.f, 0.f, 0.f};

    for (int kc = 0; kc < K_DIM / 32; kc++) {
        const int k0 = kc * 32;
        __syncthreads();                      // prev iter's ds_reads done
        GLDS16(Ah + a0 + k0, lAh0);
        GLDS16(Ah + a1 + k0, lAh1);
        GLDS16(Al + a0 + k0, lAl0);
        GLDS16(Al + a1 + k0, lAl1);
        GLDS16(Bh + b0 + k0, lBh0);
        GLDS16(Bh + b1 + k0, lBh1);
        GLDS16(Bl + b0 + k0, lBl0);
        GLDS16(Bl + b1 + k0, lBl1);
        __syncthreads();                      // vmcnt(0) drain -> tile ready

        bf16x8 fah[4], fal[4], fbh[4], fbl[4];
#pragma unroll
        for (int ti = 0; ti < 4; ti++) {
            const int ta = wm * 4 + ti;
            fah[ti] = *(const bf16x8*)&sAh[(ta * 64 + lane) * 8];
            fal[ti] = *(const bf16x8*)&sAl[(ta * 64 + lane) * 8];
        }
#pragma unroll
        for (int tj = 0; tj < 4; tj++) {
            const int tb = wn * 4 + tj;
            fbh[tj] = *(const bf16x8*)&sBh[(tb * 64 + lane) * 8];
            fbl[tj] = *(const bf16x8*)&sBl[(tb * 64 + lane) * 8];
        }
#pragma unroll
        for (int ti = 0; ti < 4; ti++)
#pragma unroll
            for (int tj = 0; tj < 4; tj++) {
                acc[ti][tj] = __builtin_amdgcn_mfma_f32_16x16x32_bf16(
                    fah[ti], fbh[tj], acc[ti][tj], 0, 0, 0);
                acc[ti][tj] = __builtin_amdgcn_mfma_f32_16x16x32_bf16(
                    fah[ti], fbl[tj], acc[ti][tj], 0, 0, 0);
                acc[ti][tj] = __builtin_amdgcn_mfma_f32_16x16x32_bf16(
                    fal[ti], fbh[tj], acc[ti][tj], 0, 0, 0);
            }
    }

#pragma unroll
    for (int tj = 0; tj < 4; tj++) {
        const int n  = n0 + wn * 64 + tj * 16 + (lane & 15);
        const float bv = bias[n];
#pragma unroll
        for (int ti = 0; ti < 4; ti++) {
            const int mbase = m0 + wm * 64 + ti * 16 + (lane >> 4) * 4;
#pragma unroll
            for (int r = 0; r < 4; r++)
                C[(size_t)(mbase + r) * N_DIM + n] = acc[ti][tj][r] + bv;
        }
    }
}

// ---------------------------------------------------------------------------
// k4: banded scan; flagged chains go to per-b worklists.
// ---------------------------------------------------------------------------
__global__ __launch_bounds__(256)
void lif_scan_band(float* __restrict__ buf, unsigned int* __restrict__ counters,
                   unsigned int* __restrict__ worklist) {
    const int idx = blockIdx.x * 256 + threadIdx.x;   // chain = b*2048 + o
    float mem = 0.0f;
    bool flag = false;
#pragma unroll
    for (int t = 0; t < T_STEPS; t++) {
        const size_t off = (size_t)t * NCHAIN + idx;
        mem = __fadd_rn(__fmul_rn(mem, DECAY_F32), buf[off]);
        const float d = __fsub_rn(mem, 1.0f);
        const bool spk = d > 0.0f;
        if (fabsf(d) < BAND) flag = true;
        buf[off] = spk ? 1.0f : 0.0f;
        if (spk) mem = __fsub_rn(mem, 1.0f);
    }
    if (flag) {
        const int b = idx >> 11, o = idx & 2047;
        const unsigned int p = atomicAdd(&counters[b], 1u);
        worklist[b * 2048 + p] = (unsigned int)o;
    }
}

// ---------------------------------------------------------------------------
// k5: b-grouped exact repair. Block = (b, group-stride j). 256 thr = 64t x 4oi;
// each thread computes 4 exact Q=320-panel dots from LDS-staged X/W chunks.
// ---------------------------------------------------------------------------
#define RG 16    // chains per group
#define RJ 4     // block-strides per b
#define BKR 64   // k-chunk (320 = 5*64: panel boundaries land on chunk edges)

__global__ __launch_bounds__(256)
void lif_repair2(const float* __restrict__ X, const float* __restrict__ W,
                 const float* __restrict__ bias,
                 const unsigned int* __restrict__ counters,
                 const unsigned int* __restrict__ worklist,
                 float* __restrict__ out) {
    __shared__ float sX[BKR][T_STEPS + 1];      // [k][t] 16.25 KiB
    __shared__ float sW[RG][BKR + 1];           // [o][k]  4.06 KiB
    __shared__ float scur[T_STEPS][RG + 1];
    __shared__ float sspk[T_STEPS][RG + 1];
    __shared__ int   so[RG];

    const int b = blockIdx.x / RJ;
    const int j = blockIdx.x % RJ;
    const unsigned int n_b = counters[b];
    if (n_b == 0) return;
    const int ngroups = (int)(n_b + RG - 1) / RG;

    const int tid = threadIdx.x;
    const int t   = tid & 63;
    const int oi  = tid >> 6;          // 0..3, owns o-slots 4*oi .. 4*oi+3

    for (int g = j; g < ngroups; g += RJ) {
        if (tid < RG) {
            const int slot = g * RG + tid;
            so[tid] = (slot < (int)n_b) ? (int)worklist[b * 2048 + slot] : -1;
        }
        __syncthreads();

        float Csum[4] = {0.f, 0.f, 0.f, 0.f};
        float P[4]    = {0.f, 0.f, 0.f, 0.f};

        for (int c = 0; c < K_DIM / BKR; c++) {
            if (c > 0 && (c % 5) == 0) {       // k = 320*j panel boundary
#pragma unroll
                for (int q = 0; q < 4; q++) {
                    Csum[q] = __fadd_rn(Csum[q], P[q]);
                    P[q] = 0.f;
                }
            }
            const int k0 = c * BKR;
            // stage X chunk: 64 t x 64 k, 4 float4 per thread
            {
                const int ts = tid & 63;
                const int kq = (tid >> 6) * 16;
                const float* src = &X[(size_t)(ts * BATCH + b) * K_DIM + k0 + kq];
#pragma unroll
                for (int q = 0; q < 4; q++) {
                    const float4 v = *(const float4*)(src + q * 4);
                    sX[kq + q * 4 + 0][ts] = v.x;
                    sX[kq + q * 4 + 1][ts] = v.y;
                    sX[kq + q * 4 + 2][ts] = v.z;
                    sX[kq + q * 4 + 3][ts] = v.w;
                }
            }
            // stage W chunk: 16 o x 64 k, 1 float4 per thread
            {
                const int wo  = tid >> 4;          // 0..15
                const int wkq = (tid & 15) * 4;    // 0..60
                const int o   = so[wo];
                float4 v = {0.f, 0.f, 0.f, 0.f};
                if (o >= 0) v = *(const float4*)&W[(size_t)o * K_DIM + k0 + wkq];
                sW[wo][wkq + 0] = v.x; sW[wo][wkq + 1] = v.y;
                sW[wo][wkq + 2] = v.z; sW[wo][wkq + 3] = v.w;
            }
            __syncthreads();
            // exact sequential-k FMA, 4 independent chains (ILP)
#pragma unroll 8
            for (int k = 0; k < BKR; k++) {
                const float xv = sX[k][t];
#pragma unroll
                for (int q = 0; q < 4; q++)
                    P[q] = fmaf(xv, sW[oi * 4 + q][k], P[q]);
            }
            __syncthreads();
        }
#pragma unroll
        for (int q = 0; q < 4; q++) {
            Csum[q] = __fadd_rn(Csum[q], P[q]);    // final 128-elem panel
            const int o = so[oi * 4 + q];
            scur[t][oi * 4 + q] = (o >= 0) ? __fadd_rn(Csum[q], bias[o]) : 0.f;
        }
        __syncthreads();
        if (tid < RG && so[tid] >= 0) {
            float mem = 0.0f;
            for (int tt = 0; tt < T_STEPS; tt++) {
                mem = __fadd_rn(__fmul_rn(mem, DECAY_F32), scur[tt][tid]);
                const float d = __fsub_rn(mem, 1.0f);
                const bool spk = d > 0.0f;
                sspk[tt][tid] = spk ? 1.0f : 0.0f;
                if (spk) mem = __fsub_rn(mem, 1.0f);
            }
        }
        __syncthreads();
#pragma unroll
        for (int q = 0; q < 4; q++) {
            const int o = so[oi * 4 + q];
            if (o >= 0)
                out[(size_t)t * NCHAIN + (size_t)b * N_DIM + o] = sspk[t][oi * 4 + q];
        }
        __syncthreads();
    }
}

// ---------------------------------------------------------------------------
// FALLBACK (R8, known-passing, ws-free).
// ---------------------------------------------------------------------------
__global__ __launch_bounds__(256)
void lif_openblas_q320(const float* __restrict__ X, const float* __restrict__ W,
                       const float* __restrict__ bias, float* __restrict__ out) {
    __shared__ float As[16][T_STEPS + 4];
    __shared__ float Ws[16][64 + 4];
    __shared__ float curbuf[T_STEPS][64 + 1];
    const int tid = threadIdx.x;
    const int o0 = blockIdx.x * 64, b0 = blockIdx.y;
    const int tm = (tid & 15) * 4, tn = (tid >> 4) * 4;
    float Csum[4][4], Pacc[4][4];
#pragma unroll
    for (int i = 0; i < 4; i++)
#pragma unroll
        for (int j = 0; j < 4; j++) { Csum[i][j] = 0.f; Pacc[i][j] = 0.f; }
    for (int c = 0; c < K_DIM / 16; c++) {
        if (c > 0 && (c % 20) == 0) {
#pragma unroll
            for (int i = 0; i < 4; i++)
#pragma unroll
                for (int j = 0; j < 4; j++) {
                    Csum[i][j] = __fadd_rn(Csum[i][j], Pacc[i][j]);
                    Pacc[i][j] = 0.f;
                }
        }
        const int k0 = c * 16;
        {
            const int t = tid >> 2, kq = (tid & 3) * 4;
            const float4 av = *(const float4*)&X[(size_t)(t * BATCH + b0) * K_DIM + k0 + kq];
            As[kq + 0][t] = av.x; As[kq + 1][t] = av.y;
            As[kq + 2][t] = av.z; As[kq + 3][t] = av.w;
            const float4 wv = *(const float4*)&W[(size_t)(o0 + t) * K_DIM + k0 + kq];
            Ws[kq + 0][t] = wv.x; Ws[kq + 1][t] = wv.y;
            Ws[kq + 2][t] = wv.z; Ws[kq + 3][t] = wv.w;
        }
        __syncthreads();
#pragma unroll
        for (int k = 0; k < 16; k++) {
            float a[4], w[4];
#pragma unroll
            for (int i = 0; i < 4; i++) a[i] = As[k][tm + i];
#pragma unroll
            for (int j = 0; j < 4; j++) w[j] = Ws[k][tn + j];
#pragma unroll
            for (int i = 0; i < 4; i++)
#pragma unroll
                for (int j = 0; j < 4; j++) Pacc[i][j] = fmaf(a[i], w[j], Pacc[i][j]);
        }
        __syncthreads();
    }
#pragma unroll
    for (int i = 0; i < 4; i++)
#pragma unroll
        for (int j = 0; j < 4; j++)
            curbuf[tm + i][tn + j] =
                __fadd_rn(__fadd_rn(Csum[i][j], Pacc[i][j]), bias[o0 + tn + j]);
    __syncthreads();
    if (tid < 64) {
        float mem = 0.0f;
#pragma unroll
        for (int t = 0; t < T_STEPS; t++) {
            mem = __fadd_rn(__fmul_rn(mem, DECAY_F32), curbuf[t][tid]);
            const float d = __fsub_rn(mem, 1.0f);
            const bool spk = d > 0.0f;
            out[(size_t)t * NCHAIN + (size_t)b0 * N_DIM + o0 + tid] = spk ? 1.0f : 0.0f;
            if (spk) mem = __fsub_rn(mem, 1.0f);
        }
    }
}

extern "C" void kernel_launch(void* const* d_in, const int* in_sizes, int n_in,
                              void* d_out, int out_size, void* d_ws, size_t ws_size,
                              hipStream_t stream) {
    const float* x = nullptr; const float* W = nullptr; const float* bias = nullptr;
    for (int i = 0; i < n_in; i++) {
        if      (in_sizes[i] == M_DIM * K_DIM) x    = (const float*)d_in[i];
        else if (in_sizes[i] == N_DIM * K_DIM) W    = (const float*)d_in[i];
        else if (in_sizes[i] == N_DIM)         bias = (const float*)d_in[i];
    }
    if (!x)    x    = (const float*)d_in[0];
    if (!W)    W    = (const float*)d_in[1];
    if (!bias) bias = (const float*)d_in[2];
    float* out = (float*)d_out;

    // workspace layout
    const size_t off_cnt = 0;                                     // 128 u32
    const size_t off_wl  = 512;                                   // 128*2048 u32
    const size_t off_Ah  = off_wl + (size_t)128 * 2048 * 4;       // 1049088
    const size_t szA     = (size_t)M_DIM * K_DIM * 2;             // 32 MiB
    const size_t szW     = (size_t)N_DIM * K_DIM * 2;             //  8 MiB
    const size_t off_Al  = off_Ah + szA;
    const size_t off_Wh  = off_Al + szA;
    const size_t off_Wl  = off_Wh + szW;
    const size_t need    = off_Wl + szW;

    if (ws_size < need) {
        dim3 grid(N_DIM / 64, BATCH);
        lif_openblas_q320<<<grid, 256, 0, stream>>>(x, W, bias, out);
        return;
    }

    char* ws = (char*)d_ws;
    unsigned int* counters = (unsigned int*)(ws + off_cnt);
    unsigned int* worklist = (unsigned int*)(ws + off_wl);
    u16* Ah = (u16*)(ws + off_Ah);
    u16* Al = (u16*)(ws + off_Al);
    u16* Wh = (u16*)(ws + off_Wh);
    u16* Wl = (u16*)(ws + off_Wl);

    zero_counters<<<1, 128, 0, stream>>>(counters);
    split_bf16<<<(M_DIM * K_DIM / 4 + N_DIM * K_DIM / 4) / 256, 256, 0, stream>>>(
        x, W, Ah, Al, Wh, Wl);
    dim3 ggrid(N_DIM / 128, M_DIM / 128);   // (16, 64)
    gemm_bf16x3<<<ggrid, 256, 0, stream>>>(Ah, Al, Wh, Wl, bias, out);
    lif_scan_band<<<NCHAIN / 256, 256, 0, stream>>>(out, counters, worklist);
    lif_repair2<<<128 * RJ, 256, 0, stream>>>(x, W, bias, counters, worklist, out);
}

// Round 4
// 534.775 us; speedup vs baseline: 1.0375x; 1.0277x over previous
//
#include <hip/hip_runtime.h>
#include <hip/hip_bf16.h>
#include <math.h>

// ---------------------------------------------------------------------------
// LIF layer, round 14: bf16x3 MFMA GEMM with DOUBLE-BUFFERED LDS +
// prefetch-under-MFMA (1 barrier/K-step) + banded scan + b-grouped repair.
//
// R13 post-mortem: gload_lds with 2 barriers/step was NEUTRAL (285us,
// MfmaUtil 31%) — loads issue after barrier-1 and drain at barrier-2 with
// nothing in between; ~300cy L2 latency fully exposed per K-step.
// R14: double-buffer LDS (64 KiB), issue next-step's 8 global_load_lds
// BEFORE the MFMA cluster; the __syncthreads vmcnt(0) drain at the TOP of
// the next iteration is then harmless (load is ~430cy old). One barrier
// per K-step. MFMA sequence bitwise identical to R10/R13 -> absmax 0.0.
//
// Pipeline:
//   k1 zero    : 128 per-b worklist counters = 0
//   k2 split   : X,W f32 -> bf16 hi/lo (Dekker, exact residual)
//   k3 gemm    : 128x128x32 MFMA tiles, hh+hl+lh, dbuf gload_lds prefetch
//   k4 scan    : exact-f32 scan, spikes in place, tight chains -> worklist[b]
//   k5 repair  : per (b, group of 16 chains): exact Q=320-panel dots from
//                LDS-staged X (64t x 64k chunks), exact scan, overwrite.
// Fallback (ws too small): R8 fused exact kernel (known-passing).
// ---------------------------------------------------------------------------

typedef unsigned short u16;
typedef __attribute__((ext_vector_type(8))) short bf16x8;
typedef __attribute__((ext_vector_type(4))) float f32x4;

constexpr int T_STEPS = 64;
constexpr int BATCH   = 128;
constexpr int K_DIM   = 2048;
constexpr int N_DIM   = 2048;
constexpr int M_DIM   = T_STEPS * BATCH;      // 8192
constexpr int NCHAIN  = BATCH * N_DIM;        // 262144

constexpr float DECAY_F32 = (float)0.6065306597126334;
constexpr float BAND      = 5e-4f;

#define GLDS16(g, l) __builtin_amdgcn_global_load_lds(                       \
    (const __attribute__((address_space(1))) void*)(g),                      \
    (__attribute__((address_space(3))) void*)(l), 16, 0, 0)

// ---------------------------------------------------------------------------
__global__ void zero_counters(unsigned int* p) {
    if (threadIdx.x < 128) p[threadIdx.x] = 0u;
}

// ---------------------------------------------------------------------------
// k2: Dekker split f32 -> bf16 hi/lo, 4 elems/thread. (R10, verbatim)
// ---------------------------------------------------------------------------
__global__ __launch_bounds__(256)
void split_bf16(const float* __restrict__ X, const float* __restrict__ W,
                u16* __restrict__ Ah, u16* __restrict__ Al,
                u16* __restrict__ Wh, u16* __restrict__ Wl) {
    constexpr int NA4 = (M_DIM * K_DIM) / 4;
    constexpr int NW4 = (N_DIM * K_DIM) / 4;
    const int i = blockIdx.x * 256 + threadIdx.x;
    const float* src; u16* dh; u16* dl; int base;
    if (i < NA4)            { src = X; dh = Ah; dl = Al; base = i; }
    else if (i < NA4 + NW4) { src = W; dh = Wh; dl = Wl; base = i - NA4; }
    else return;

    const float4 v = *(const float4*)(src + (size_t)base * 4);
    const float f[4] = {v.x, v.y, v.z, v.w};
    unsigned int hp[2], lp[2];
#pragma unroll
    for (int q = 0; q < 4; q += 2) {
        u16 hh[2], ll[2];
#pragma unroll
        for (int e = 0; e < 2; e++) {
            __hip_bfloat16 hb = __float2bfloat16(f[q + e]);
            const float hf = __bfloat162float(hb);
            __hip_bfloat16 lb = __float2bfloat16(f[q + e] - hf);
            hh[e] = *(u16*)&hb;
            ll[e] = *(u16*)&lb;
        }
        hp[q >> 1] = (unsigned int)hh[0] | ((unsigned int)hh[1] << 16);
        lp[q >> 1] = (unsigned int)ll[0] | ((unsigned int)ll[1] << 16);
    }
    *(uint2*)(dh + (size_t)base * 4) = make_uint2(hp[0], hp[1]);
    *(uint2*)(dl + (size_t)base * 4) = make_uint2(lp[0], lp[1]);
}

// ---------------------------------------------------------------------------
// k3: bf16x3 MFMA GEMM (hh + hl + lh). 128x128 tile, BK=32, 4 waves 2x2.
// Double-buffered LDS (2 x 32 KiB), gload_lds(16B) staging, prefetch of
// step kc+1 issued BEFORE the MFMA cluster of step kc; single
// __syncthreads per K-step. LDS blocked layout linear in entry index c
// (u16 offset tid*8 within buffer); permutation in per-lane GLOBAL addr.
// ---------------------------------------------------------------------------
__global__ __launch_bounds__(256, 2)
void gemm_bf16x3(const u16* __restrict__ Ah, const u16* __restrict__ Al,
                 const u16* __restrict__ Bh, const u16* __restrict__ Bl,
                 const float* __restrict__ bias, float* __restrict__ C) {
    __shared__ __align__(16) u16 sAh[2][4096], sAl[2][4096];
    __shared__ __align__(16) u16 sBh[2][4096], sBl[2][4096];

    const int tid  = threadIdx.x;
    const int m0   = blockIdx.y * 128;
    const int n0   = blockIdx.x * 128;
    const int lane = tid & 63;
    const int wave = tid >> 6;
    const int wm   = wave >> 1;
    const int wn   = wave & 1;

    const int c0 = tid, c1 = tid + 256;
#define OFFA(c) ((size_t)(m0 + ((c) >> 6) * 16 + ((c) & 15)) * K_DIM + (((c) >> 4) & 3) * 8)
#define OFFB(c) ((size_t)(n0 + ((c) >> 6) * 16 + ((c) & 15)) * K_DIM + (((c) >> 4) & 3) * 8)
    const size_t a0 = OFFA(c0), a1 = OFFA(c1);
    const size_t b0 = OFFB(c0), b1 = OFFB(c1);
#undef OFFA
#undef OFFB

    // wave-uniform LDS dest offsets (u16) within a buffer; HW adds lane*16B.
    const int l0 = wave * 512;          // entries c0 = tid
    const int l1 = 2048 + wave * 512;   // entries c1 = tid + 256

    f32x4 acc[4][4];
#pragma unroll
    for (int i = 0; i < 4; i++)
#pragma unroll
        for (int j = 0; j < 4; j++) acc[i][j] = (f32x4){0.f, 0.f, 0.f, 0.f};

    // prologue: stage K-chunk 0 into buffer 0
    {
        GLDS16(Ah + a0, &sAh[0][l0]);  GLDS16(Ah + a1, &sAh[0][l1]);
        GLDS16(Al + a0, &sAl[0][l0]);  GLDS16(Al + a1, &sAl[0][l1]);
        GLDS16(Bh + b0, &sBh[0][l0]);  GLDS16(Bh + b1, &sBh[0][l1]);
        GLDS16(Bl + b0, &sBl[0][l0]);  GLDS16(Bl + b1, &sBl[0][l1]);
    }

    int cur = 0;
    for (int kc = 0; kc < K_DIM / 32; kc++) {
        __syncthreads();   // drains this wave's prefetch (issued last iter,
                           // aged under MFMA) + all waves done reading cur^1

        // fragment ds_reads from current buffer (critical path first)
        bf16x8 fah[4], fal[4], fbh[4], fbl[4];
#pragma unroll
        for (int ti = 0; ti < 4; ti++) {
            const int ta = wm * 4 + ti;
            fah[ti] = *(const bf16x8*)&sAh[cur][(ta * 64 + lane) * 8];
            fal[ti] = *(const bf16x8*)&sAl[cur][(ta * 64 + lane) * 8];
        }
#pragma unroll
        for (int tj = 0; tj < 4; tj++) {
            const int tb = wn * 4 + tj;
            fbh[tj] = *(const bf16x8*)&sBh[cur][(tb * 64 + lane) * 8];
            fbl[tj] = *(const bf16x8*)&sBl[cur][(tb * 64 + lane) * 8];
        }

        // prefetch next K-chunk into the other buffer (latency hides
        // under the MFMA cluster below; drained at next iter's barrier)
        if (kc + 1 < K_DIM / 32) {
            const int kn = (kc + 1) * 32;
            const int nx = cur ^ 1;
            GLDS16(Ah + a0 + kn, &sAh[nx][l0]);  GLDS16(Ah + a1 + kn, &sAh[nx][l1]);
            GLDS16(Al + a0 + kn, &sAl[nx][l0]);  GLDS16(Al + a1 + kn, &sAl[nx][l1]);
            GLDS16(Bh + b0 + kn, &sBh[nx][l0]);  GLDS16(Bh + b1 + kn, &sBh[nx][l1]);
            GLDS16(Bl + b0 + kn, &sBl[nx][l0]);  GLDS16(Bl + b1 + kn, &sBl[nx][l1]);
        }

#pragma unroll
        for (int ti = 0; ti < 4; ti++)
#pragma unroll
            for (int tj = 0; tj < 4; tj++) {
                acc[ti][tj] = __builtin_amdgcn_mfma_f32_16x16x32_bf16(
                    fah[ti], fbh[tj], acc[ti][tj], 0, 0, 0);
                acc[ti][tj] = __builtin_amdgcn_mfma_f32_16x16x32_bf16(
                    fah[ti], fbl[tj], acc[ti][tj], 0, 0, 0);
                acc[ti][tj] = __builtin_amdgcn_mfma_f32_16x16x32_bf16(
                    fal[ti], fbh[tj], acc[ti][tj], 0, 0, 0);
            }
        cur ^= 1;
    }

#pragma unroll
    for (int tj = 0; tj < 4; tj++) {
        const int n  = n0 + wn * 64 + tj * 16 + (lane & 15);
        const float bv = bias[n];
#pragma unroll
        for (int ti = 0; ti < 4; ti++) {
            const int mbase = m0 + wm * 64 + ti * 16 + (lane >> 4) * 4;
#pragma unroll
            for (int r = 0; r < 4; r++)
                C[(size_t)(mbase + r) * N_DIM + n] = acc[ti][tj][r] + bv;
        }
    }
}

// ---------------------------------------------------------------------------
// k4: banded scan; flagged chains go to per-b worklists.
// ---------------------------------------------------------------------------
__global__ __launch_bounds__(256)
void lif_scan_band(float* __restrict__ buf, unsigned int* __restrict__ counters,
                   unsigned int* __restrict__ worklist) {
    const int idx = blockIdx.x * 256 + threadIdx.x;   // chain = b*2048 + o
    float mem = 0.0f;
    bool flag = false;
#pragma unroll
    for (int t = 0; t < T_STEPS; t++) {
        const size_t off = (size_t)t * NCHAIN + idx;
        mem = __fadd_rn(__fmul_rn(mem, DECAY_F32), buf[off]);
        const float d = __fsub_rn(mem, 1.0f);
        const bool spk = d > 0.0f;
        if (fabsf(d) < BAND) flag = true;
        buf[off] = spk ? 1.0f : 0.0f;
        if (spk) mem = __fsub_rn(mem, 1.0f);
    }
    if (flag) {
        const int b = idx >> 11, o = idx & 2047;
        const unsigned int p = atomicAdd(&counters[b], 1u);
        worklist[b * 2048 + p] = (unsigned int)o;
    }
}

// ---------------------------------------------------------------------------
// k5: b-grouped exact repair. Block = (b, group-stride j). 256 thr = 64t x 4oi;
// each thread computes 4 exact Q=320-panel dots from LDS-staged X/W chunks.
// ---------------------------------------------------------------------------
#define RG 16    // chains per group
#define RJ 4     // block-strides per b
#define BKR 64   // k-chunk (320 = 5*64: panel boundaries land on chunk edges)

__global__ __launch_bounds__(256)
void lif_repair2(const float* __restrict__ X, const float* __restrict__ W,
                 const float* __restrict__ bias,
                 const unsigned int* __restrict__ counters,
                 const unsigned int* __restrict__ worklist,
                 float* __restrict__ out) {
    __shared__ float sX[BKR][T_STEPS + 1];      // [k][t] 16.25 KiB
    __shared__ float sW[RG][BKR + 1];           // [o][k]  4.06 KiB
    __shared__ float scur[T_STEPS][RG + 1];
    __shared__ float sspk[T_STEPS][RG + 1];
    __shared__ int   so[RG];

    const int b = blockIdx.x / RJ;
    const int j = blockIdx.x % RJ;
    const unsigned int n_b = counters[b];
    if (n_b == 0) return;
    const int ngroups = (int)(n_b + RG - 1) / RG;

    const int tid = threadIdx.x;
    const int t   = tid & 63;
    const int oi  = tid >> 6;          // 0..3, owns o-slots 4*oi .. 4*oi+3

    for (int g = j; g < ngroups; g += RJ) {
        if (tid < RG) {
            const int slot = g * RG + tid;
            so[tid] = (slot < (int)n_b) ? (int)worklist[b * 2048 + slot] : -1;
        }
        __syncthreads();

        float Csum[4] = {0.f, 0.f, 0.f, 0.f};
        float P[4]    = {0.f, 0.f, 0.f, 0.f};

        for (int c = 0; c < K_DIM / BKR; c++) {
            if (c > 0 && (c % 5) == 0) {       // k = 320*j panel boundary
#pragma unroll
                for (int q = 0; q < 4; q++) {
                    Csum[q] = __fadd_rn(Csum[q], P[q]);
                    P[q] = 0.f;
                }
            }
            const int k0 = c * BKR;
            // stage X chunk: 64 t x 64 k, 4 float4 per thread
            {
                const int ts = tid & 63;
                const int kq = (tid >> 6) * 16;
                const float* src = &X[(size_t)(ts * BATCH + b) * K_DIM + k0 + kq];
#pragma unroll
                for (int q = 0; q < 4; q++) {
                    const float4 v = *(const float4*)(src + q * 4);
                    sX[kq + q * 4 + 0][ts] = v.x;
                    sX[kq + q * 4 + 1][ts] = v.y;
                    sX[kq + q * 4 + 2][ts] = v.z;
                    sX[kq + q * 4 + 3][ts] = v.w;
                }
            }
            // stage W chunk: 16 o x 64 k, 1 float4 per thread
            {
                const int wo  = tid >> 4;          // 0..15
                const int wkq = (tid & 15) * 4;    // 0..60
                const int o   = so[wo];
                float4 v = {0.f, 0.f, 0.f, 0.f};
                if (o >= 0) v = *(const float4*)&W[(size_t)o * K_DIM + k0 + wkq];
                sW[wo][wkq + 0] = v.x; sW[wo][wkq + 1] = v.y;
                sW[wo][wkq + 2] = v.z; sW[wo][wkq + 3] = v.w;
            }
            __syncthreads();
            // exact sequential-k FMA, 4 independent chains (ILP)
#pragma unroll 8
            for (int k = 0; k < BKR; k++) {
                const float xv = sX[k][t];
#pragma unroll
                for (int q = 0; q < 4; q++)
                    P[q] = fmaf(xv, sW[oi * 4 + q][k], P[q]);
            }
            __syncthreads();
        }
#pragma unroll
        for (int q = 0; q < 4; q++) {
            Csum[q] = __fadd_rn(Csum[q], P[q]);    // final 128-elem panel
            const int o = so[oi * 4 + q];
            scur[t][oi * 4 + q] = (o >= 0) ? __fadd_rn(Csum[q], bias[o]) : 0.f;
        }
        __syncthreads();
        if (tid < RG && so[tid] >= 0) {
            float mem = 0.0f;
            for (int tt = 0; tt < T_STEPS; tt++) {
                mem = __fadd_rn(__fmul_rn(mem, DECAY_F32), scur[tt][tid]);
                const float d = __fsub_rn(mem, 1.0f);
                const bool spk = d > 0.0f;
                sspk[tt][tid] = spk ? 1.0f : 0.0f;
                if (spk) mem = __fsub_rn(mem, 1.0f);
            }
        }
        __syncthreads();
#pragma unroll
        for (int q = 0; q < 4; q++) {
            const int o = so[oi * 4 + q];
            if (o >= 0)
                out[(size_t)t * NCHAIN + (size_t)b * N_DIM + o] = sspk[t][oi * 4 + q];
        }
        __syncthreads();
    }
}

// ---------------------------------------------------------------------------
// FALLBACK (R8, known-passing, ws-free).
// ---------------------------------------------------------------------------
__global__ __launch_bounds__(256)
void lif_openblas_q320(const float* __restrict__ X, const float* __restrict__ W,
                       const float* __restrict__ bias, float* __restrict__ out) {
    __shared__ float As[16][T_STEPS + 4];
    __shared__ float Ws[16][64 + 4];
    __shared__ float curbuf[T_STEPS][64 + 1];
    const int tid = threadIdx.x;
    const int o0 = blockIdx.x * 64, b0 = blockIdx.y;
    const int tm = (tid & 15) * 4, tn = (tid >> 4) * 4;
    float Csum[4][4], Pacc[4][4];
#pragma unroll
    for (int i = 0; i < 4; i++)
#pragma unroll
        for (int j = 0; j < 4; j++) { Csum[i][j] = 0.f; Pacc[i][j] = 0.f; }
    for (int c = 0; c < K_DIM / 16; c++) {
        if (c > 0 && (c % 20) == 0) {
#pragma unroll
            for (int i = 0; i < 4; i++)
#pragma unroll
                for (int j = 0; j < 4; j++) {
                    Csum[i][j] = __fadd_rn(Csum[i][j], Pacc[i][j]);
                    Pacc[i][j] = 0.f;
                }
        }
        const int k0 = c * 16;
        {
            const int t = tid >> 2, kq = (tid & 3) * 4;
            const float4 av = *(const float4*)&X[(size_t)(t * BATCH + b0) * K_DIM + k0 + kq];
            As[kq + 0][t] = av.x; As[kq + 1][t] = av.y;
            As[kq + 2][t] = av.z; As[kq + 3][t] = av.w;
            const float4 wv = *(const float4*)&W[(size_t)(o0 + t) * K_DIM + k0 + kq];
            Ws[kq + 0][t] = wv.x; Ws[kq + 1][t] = wv.y;
            Ws[kq + 2][t] = wv.z; Ws[kq + 3][t] = wv.w;
        }
        __syncthreads();
#pragma unroll
        for (int k = 0; k < 16; k++) {
            float a[4], w[4];
#pragma unroll
            for (int i = 0; i < 4; i++) a[i] = As[k][tm + i];
#pragma unroll
            for (int j = 0; j < 4; j++) w[j] = Ws[k][tn + j];
#pragma unroll
            for (int i = 0; i < 4; i++)
#pragma unroll
                for (int j = 0; j < 4; j++) Pacc[i][j] = fmaf(a[i], w[j], Pacc[i][j]);
        }
        __syncthreads();
    }
#pragma unroll
    for (int i = 0; i < 4; i++)
#pragma unroll
        for (int j = 0; j < 4; j++)
            curbuf[tm + i][tn + j] =
                __fadd_rn(__fadd_rn(Csum[i][j], Pacc[i][j]), bias[o0 + tn + j]);
    __syncthreads();
    if (tid < 64) {
        float mem = 0.0f;
#pragma unroll
        for (int t = 0; t < T_STEPS; t++) {
            mem = __fadd_rn(__fmul_rn(mem, DECAY_F32), curbuf[t][tid]);
            const float d = __fsub_rn(mem, 1.0f);
            const bool spk = d > 0.0f;
            out[(size_t)t * NCHAIN + (size_t)b0 * N_DIM + o0 + tid] = spk ? 1.0f : 0.0f;
            if (spk) mem = __fsub_rn(mem, 1.0f);
        }
    }
}

extern "C" void kernel_launch(void* const* d_in, const int* in_sizes, int n_in,
                              void* d_out, int out_size, void* d_ws, size_t ws_size,
                              hipStream_t stream) {
    const float* x = nullptr; const float* W = nullptr; const float* bias = nullptr;
    for (int i = 0; i < n_in; i++) {
        if      (in_sizes[i] == M_DIM * K_DIM) x    = (const float*)d_in[i];
        else if (in_sizes[i] == N_DIM * K_DIM) W    = (const float*)d_in[i];
        else if (in_sizes[i] == N_DIM)         bias = (const float*)d_in[i];
    }
    if (!x)    x    = (const float*)d_in[0];
    if (!W)    W    = (const float*)d_in[1];
    if (!bias) bias = (const float*)d_in[2];
    float* out = (float*)d_out;

    // workspace layout
    const size_t off_cnt = 0;                                     // 128 u32
    const size_t off_wl  = 512;                                   // 128*2048 u32
    const size_t off_Ah  = off_wl + (size_t)128 * 2048 * 4;       // 1049088
    const size_t szA     = (size_t)M_DIM * K_DIM * 2;             // 32 MiB
    const size_t szW     = (size_t)N_DIM * K_DIM * 2;             //  8 MiB
    const size_t off_Al  = off_Ah + szA;
    const size_t off_Wh  = off_Al + szA;
    const size_t off_Wl  = off_Wh + szW;
    const size_t need    = off_Wl + szW;

    if (ws_size < need) {
        dim3 grid(N_DIM / 64, BATCH);
        lif_openblas_q320<<<grid, 256, 0, stream>>>(x, W, bias, out);
        return;
    }

    char* ws = (char*)d_ws;
    unsigned int* counters = (unsigned int*)(ws + off_cnt);
    unsigned int* worklist = (unsigned int*)(ws + off_wl);
    u16* Ah = (u16*)(ws + off_Ah);
    u16* Al = (u16*)(ws + off_Al);
    u16* Wh = (u16*)(ws + off_Wh);
    u16* Wl = (u16*)(ws + off_Wl);

    zero_counters<<<1, 128, 0, stream>>>(counters);
    split_bf16<<<(M_DIM * K_DIM / 4 + N_DIM * K_DIM / 4) / 256, 256, 0, stream>>>(
        x, W, Ah, Al, Wh, Wl);
    dim3 ggrid(N_DIM / 128, M_DIM / 128);   // (16, 64)
    gemm_bf16x3<<<ggrid, 256, 0, stream>>>(Ah, Al, Wh, Wl, bias, out);
    lif_scan_band<<<NCHAIN / 256, 256, 0, stream>>>(out, counters, worklist);
    lif_repair2<<<128 * RJ, 256, 0, stream>>>(x, W, bias, counters, worklist, out);
}

// Round 5
// 481.556 us; speedup vs baseline: 1.1521x; 1.1105x over previous
//
#include <hip/hip_runtime.h>
#include <hip/hip_bf16.h>
#include <math.h>

// ---------------------------------------------------------------------------
// LIF layer, round 15: bf16x3 MFMA GEMM with 3-STAGE RING PIPELINE
// (depth-2 prefetch, counted s_waitcnt vmcnt(6), raw s_barrier, setprio)
// + banded scan + b-grouped exact repair.
//
// R13/R14 post-mortem: both 2-barrier and 2-buffer/1-barrier variants sit at
// ~750 TF / 31% MfmaUtil — the documented m97-structure ceiling. With 2
// buffers the prefetch can only age ONE MFMA cluster (~233cy) before the
// barrier drain needs it (< load latency). T3+T4 (counted vmcnt, never 0 in
// main loop; >=2 steps in flight) is the verified escape (+38-73%, m218).
//
// R15 gemm: 256x128 tile, 8 waves (512 thr), BK=32, 3-stage LDS ring
// (48 KiB/stage, 144 KiB dynamic LDS, 1 block/CU). Per K-step:
//   s_waitcnt vmcnt(6)        // stage kc's 6 loads landed (in-order ctr)
//   s_barrier                 // block-wide: stage kc readable, kc-1 free
//   STAGE(kc+2)               // 6 global_load_lds into freed buffer
//   ds_read frags(kc%3); setprio(1); 48 MFMA; setprio(0)
// Loads age ~2 MFMA clusters before use. MFMA sequence per output element
// bitwise identical to R10/R13/R14 -> absmax 0.0.
//
// Pipeline: k1 zero / k2 split / k3 gemm / k4 scan / k5 repair.
// Fallback (ws too small): R8 fused exact kernel (known-passing).
// ---------------------------------------------------------------------------

typedef unsigned short u16;
typedef __attribute__((ext_vector_type(8))) short bf16x8;
typedef __attribute__((ext_vector_type(4))) float f32x4;

constexpr int T_STEPS = 64;
constexpr int BATCH   = 128;
constexpr int K_DIM   = 2048;
constexpr int N_DIM   = 2048;
constexpr int M_DIM   = T_STEPS * BATCH;      // 8192
constexpr int NCHAIN  = BATCH * N_DIM;        // 262144

constexpr float DECAY_F32 = (float)0.6065306597126334;
constexpr float BAND      = 5e-4f;

#define GLDS16(g, l) __builtin_amdgcn_global_load_lds(                       \
    (const __attribute__((address_space(1))) void*)(g),                      \
    (__attribute__((address_space(3))) void*)(l), 16, 0, 0)

// ---------------------------------------------------------------------------
__global__ void zero_counters(unsigned int* p) {
    if (threadIdx.x < 128) p[threadIdx.x] = 0u;
}

// ---------------------------------------------------------------------------
// k2: Dekker split f32 -> bf16 hi/lo, 4 elems/thread. (R10, verbatim)
// ---------------------------------------------------------------------------
__global__ __launch_bounds__(256)
void split_bf16(const float* __restrict__ X, const float* __restrict__ W,
                u16* __restrict__ Ah, u16* __restrict__ Al,
                u16* __restrict__ Wh, u16* __restrict__ Wl) {
    constexpr int NA4 = (M_DIM * K_DIM) / 4;
    constexpr int NW4 = (N_DIM * K_DIM) / 4;
    const int i = blockIdx.x * 256 + threadIdx.x;
    const float* src; u16* dh; u16* dl; int base;
    if (i < NA4)            { src = X; dh = Ah; dl = Al; base = i; }
    else if (i < NA4 + NW4) { src = W; dh = Wh; dl = Wl; base = i - NA4; }
    else return;

    const float4 v = *(const float4*)(src + (size_t)base * 4);
    const float f[4] = {v.x, v.y, v.z, v.w};
    unsigned int hp[2], lp[2];
#pragma unroll
    for (int q = 0; q < 4; q += 2) {
        u16 hh[2], ll[2];
#pragma unroll
        for (int e = 0; e < 2; e++) {
            __hip_bfloat16 hb = __float2bfloat16(f[q + e]);
            const float hf = __bfloat162float(hb);
            __hip_bfloat16 lb = __float2bfloat16(f[q + e] - hf);
            hh[e] = *(u16*)&hb;
            ll[e] = *(u16*)&lb;
        }
        hp[q >> 1] = (unsigned int)hh[0] | ((unsigned int)hh[1] << 16);
        lp[q >> 1] = (unsigned int)ll[0] | ((unsigned int)ll[1] << 16);
    }
    *(uint2*)(dh + (size_t)base * 4) = make_uint2(hp[0], hp[1]);
    *(uint2*)(dl + (size_t)base * 4) = make_uint2(lp[0], lp[1]);
}

// ---------------------------------------------------------------------------
// k3: bf16x3 MFMA GEMM (hh + hl + lh), 256x128 tile, 8 waves (4m x 2n),
// BK=32, 3-stage LDS ring + counted-vmcnt pipeline (see header).
// LDS blocked layout linear in entry index (u16 offset = entry*8 within
// stage); permutation lives in the per-lane GLOBAL address (m97 pattern).
// ---------------------------------------------------------------------------
__global__ __launch_bounds__(512, 2)
void gemm_bf16x3p(const u16* __restrict__ Ah, const u16* __restrict__ Al,
                  const u16* __restrict__ Bh, const u16* __restrict__ Bl,
                  const float* __restrict__ bias, float* __restrict__ C) {
    extern __shared__ __align__(16) u16 smem[];
    u16* const sAh = smem;                          // [3][8192]
    u16* const sAl = smem + 3 * 8192;               // [3][8192]
    u16* const sBh = smem + 6 * 8192;               // [3][4096]
    u16* const sBl = smem + 6 * 8192 + 3 * 4096;    // [3][4096]

    const int tid  = threadIdx.x;
    const int m0   = blockIdx.y * 256;
    const int n0   = blockIdx.x * 128;
    const int lane = tid & 63;
    const int wave = tid >> 6;     // 0..7
    const int wm   = wave >> 1;    // 0..3 (64-row slab)
    const int wn   = wave & 1;     // 0..1 (64-col slab)

    const int cA0 = tid, cA1 = tid + 512, cB0 = tid;
#define OFFA(c) ((size_t)(m0 + ((c) >> 6) * 16 + ((c) & 15)) * K_DIM + (((c) >> 4) & 3) * 8)
#define OFFB(c) ((size_t)(n0 + ((c) >> 6) * 16 + ((c) & 15)) * K_DIM + (((c) >> 4) & 3) * 8)
    const size_t a0 = OFFA(cA0), a1 = OFFA(cA1), b0 = OFFB(cB0);
#undef OFFA
#undef OFFB

    // wave-uniform LDS dest offsets (u16) within a stage; HW adds lane*16B.
    const int lA0 = wave * 512;
    const int lA1 = 4096 + wave * 512;
    const int lB0 = wave * 512;

    f32x4 acc[4][4];
#pragma unroll
    for (int i = 0; i < 4; i++)
#pragma unroll
        for (int j = 0; j < 4; j++) acc[i][j] = (f32x4){0.f, 0.f, 0.f, 0.f};

#define STAGE(s, kc) do {                                                    \
        const int kn_ = (kc) * 32;                                           \
        GLDS16(Ah + a0 + kn_, sAh + (s) * 8192 + lA0);                       \
        GLDS16(Ah + a1 + kn_, sAh + (s) * 8192 + lA1);                       \
        GLDS16(Al + a0 + kn_, sAl + (s) * 8192 + lA0);                       \
        GLDS16(Al + a1 + kn_, sAl + (s) * 8192 + lA1);                       \
        GLDS16(Bh + b0 + kn_, sBh + (s) * 4096 + lB0);                       \
        GLDS16(Bl + b0 + kn_, sBl + (s) * 4096 + lB0);                       \
    } while (0)

#define COMPUTE(rs) do {                                                     \
        bf16x8 fah[4], fal[4], fbh[4], fbl[4];                               \
        _Pragma("unroll")                                                    \
        for (int ti = 0; ti < 4; ti++) {                                     \
            const int ta = wm * 4 + ti;                                      \
            fah[ti] = *(const bf16x8*)&sAh[(rs) * 8192 + (ta * 64 + lane) * 8]; \
            fal[ti] = *(const bf16x8*)&sAl[(rs) * 8192 + (ta * 64 + lane) * 8]; \
        }                                                                    \
        _Pragma("unroll")                                                    \
        for (int tj = 0; tj < 4; tj++) {                                     \
            const int tb = wn * 4 + tj;                                      \
            fbh[tj] = *(const bf16x8*)&sBh[(rs) * 4096 + (tb * 64 + lane) * 8]; \
            fbl[tj] = *(const bf16x8*)&sBl[(rs) * 4096 + (tb * 64 + lane) * 8]; \
        }                                                                    \
        __builtin_amdgcn_s_setprio(1);                                       \
        _Pragma("unroll")                                                    \
        for (int ti = 0; ti < 4; ti++)                                       \
        _Pragma("unroll")                                                    \
        for (int tj = 0; tj < 4; tj++) {                                     \
            acc[ti][tj] = __builtin_amdgcn_mfma_f32_16x16x32_bf16(           \
                fah[ti], fbh[tj], acc[ti][tj], 0, 0, 0);                     \
            acc[ti][tj] = __builtin_amdgcn_mfma_f32_16x16x32_bf16(           \
                fah[ti], fbl[tj], acc[ti][tj], 0, 0, 0);                     \
            acc[ti][tj] = __builtin_amdgcn_mfma_f32_16x16x32_bf16(           \
                fal[ti], fbh[tj], acc[ti][tj], 0, 0, 0);                     \
        }                                                                    \
        __builtin_amdgcn_s_setprio(0);                                       \
    } while (0)

#define SYNC(vm) do {                                                        \
        asm volatile("s_waitcnt vmcnt(" #vm ")" ::: "memory");               \
        __builtin_amdgcn_sched_barrier(0);                                   \
        __builtin_amdgcn_s_barrier();                                        \
        __builtin_amdgcn_sched_barrier(0);                                   \
    } while (0)

    // prologue: stages 0 and 1 in flight (12 outstanding loads)
    STAGE(0, 0);
    STAGE(1, 1);

    // main loop: kc = 0..62, unrolled x3 for static stage indices.
    // Invariant at top of kc: outstanding = stage kc remnants + stage kc+1's
    // six newest -> vmcnt(6) proves stage kc fully landed (in-order counter).
    for (int kcb = 0; kcb < 63; kcb += 3) {
        // kc = kcb: read stage 0, write stage 2
        SYNC(6);
        STAGE(2, kcb + 2);
        COMPUTE(0);
        // kc = kcb+1: read stage 1, write stage 0
        SYNC(6);
        STAGE(0, kcb + 3);
        COMPUTE(1);
        // kc = kcb+2: read stage 2, write stage 1
        SYNC(6);
        if (kcb + 4 < 64) STAGE(1, kcb + 4);
        COMPUTE(2);
    }
    // peeled kc = 63: read stage 0 (filled at kc=61); nothing newer in flight
    SYNC(0);
    COMPUTE(0);

#undef SYNC
#undef COMPUTE
#undef STAGE

#pragma unroll
    for (int tj = 0; tj < 4; tj++) {
        const int n  = n0 + wn * 64 + tj * 16 + (lane & 15);
        const float bv = bias[n];
#pragma unroll
        for (int ti = 0; ti < 4; ti++) {
            const int mbase = m0 + wm * 64 + ti * 16 + (lane >> 4) * 4;
#pragma unroll
            for (int r = 0; r < 4; r++)
                C[(size_t)(mbase + r) * N_DIM + n] = acc[ti][tj][r] + bv;
        }
    }
}

// ---------------------------------------------------------------------------
// k4: banded scan; flagged chains go to per-b worklists.
// ---------------------------------------------------------------------------
__global__ __launch_bounds__(256)
void lif_scan_band(float* __restrict__ buf, unsigned int* __restrict__ counters,
                   unsigned int* __restrict__ worklist) {
    const int idx = blockIdx.x * 256 + threadIdx.x;   // chain = b*2048 + o
    float mem = 0.0f;
    bool flag = false;
#pragma unroll
    for (int t = 0; t < T_STEPS; t++) {
        const size_t off = (size_t)t * NCHAIN + idx;
        mem = __fadd_rn(__fmul_rn(mem, DECAY_F32), buf[off]);
        const float d = __fsub_rn(mem, 1.0f);
        const bool spk = d > 0.0f;
        if (fabsf(d) < BAND) flag = true;
        buf[off] = spk ? 1.0f : 0.0f;
        if (spk) mem = __fsub_rn(mem, 1.0f);
    }
    if (flag) {
        const int b = idx >> 11, o = idx & 2047;
        const unsigned int p = atomicAdd(&counters[b], 1u);
        worklist[b * 2048 + p] = (unsigned int)o;
    }
}

// ---------------------------------------------------------------------------
// k5: b-grouped exact repair. Block = (b, group-stride j). 256 thr = 64t x 4oi;
// each thread computes 4 exact Q=320-panel dots from LDS-staged X/W chunks.
// ---------------------------------------------------------------------------
#define RG 16    // chains per group
#define RJ 4     // block-strides per b
#define BKR 64   // k-chunk (320 = 5*64: panel boundaries land on chunk edges)

__global__ __launch_bounds__(256)
void lif_repair2(const float* __restrict__ X, const float* __restrict__ W,
                 const float* __restrict__ bias,
                 const unsigned int* __restrict__ counters,
                 const unsigned int* __restrict__ worklist,
                 float* __restrict__ out) {
    __shared__ float sX[BKR][T_STEPS + 1];      // [k][t] 16.25 KiB
    __shared__ float sW[RG][BKR + 1];           // [o][k]  4.06 KiB
    __shared__ float scur[T_STEPS][RG + 1];
    __shared__ float sspk[T_STEPS][RG + 1];
    __shared__ int   so[RG];

    const int b = blockIdx.x / RJ;
    const int j = blockIdx.x % RJ;
    const unsigned int n_b = counters[b];
    if (n_b == 0) return;
    const int ngroups = (int)(n_b + RG - 1) / RG;

    const int tid = threadIdx.x;
    const int t   = tid & 63;
    const int oi  = tid >> 6;          // 0..3, owns o-slots 4*oi .. 4*oi+3

    for (int g = j; g < ngroups; g += RJ) {
        if (tid < RG) {
            const int slot = g * RG + tid;
            so[tid] = (slot < (int)n_b) ? (int)worklist[b * 2048 + slot] : -1;
        }
        __syncthreads();

        float Csum[4] = {0.f, 0.f, 0.f, 0.f};
        float P[4]    = {0.f, 0.f, 0.f, 0.f};

        for (int c = 0; c < K_DIM / BKR; c++) {
            if (c > 0 && (c % 5) == 0) {       // k = 320*j panel boundary
#pragma unroll
                for (int q = 0; q < 4; q++) {
                    Csum[q] = __fadd_rn(Csum[q], P[q]);
                    P[q] = 0.f;
                }
            }
            const int k0 = c * BKR;
            // stage X chunk: 64 t x 64 k, 4 float4 per thread
            {
                const int ts = tid & 63;
                const int kq = (tid >> 6) * 16;
                const float* src = &X[(size_t)(ts * BATCH + b) * K_DIM + k0 + kq];
#pragma unroll
                for (int q = 0; q < 4; q++) {
                    const float4 v = *(const float4*)(src + q * 4);
                    sX[kq + q * 4 + 0][ts] = v.x;
                    sX[kq + q * 4 + 1][ts] = v.y;
                    sX[kq + q * 4 + 2][ts] = v.z;
                    sX[kq + q * 4 + 3][ts] = v.w;
                }
            }
            // stage W chunk: 16 o x 64 k, 1 float4 per thread
            {
                const int wo  = tid >> 4;          // 0..15
                const int wkq = (tid & 15) * 4;    // 0..60
                const int o   = so[wo];
                float4 v = {0.f, 0.f, 0.f, 0.f};
                if (o >= 0) v = *(const float4*)&W[(size_t)o * K_DIM + k0 + wkq];
                sW[wo][wkq + 0] = v.x; sW[wo][wkq + 1] = v.y;
                sW[wo][wkq + 2] = v.z; sW[wo][wkq + 3] = v.w;
            }
            __syncthreads();
            // exact sequential-k FMA, 4 independent chains (ILP)
#pragma unroll 8
            for (int k = 0; k < BKR; k++) {
                const float xv = sX[k][t];
#pragma unroll
                for (int q = 0; q < 4; q++)
                    P[q] = fmaf(xv, sW[oi * 4 + q][k], P[q]);
            }
            __syncthreads();
        }
#pragma unroll
        for (int q = 0; q < 4; q++) {
            Csum[q] = __fadd_rn(Csum[q], P[q]);    // final 128-elem panel
            const int o = so[oi * 4 + q];
            scur[t][oi * 4 + q] = (o >= 0) ? __fadd_rn(Csum[q], bias[o]) : 0.f;
        }
        __syncthreads();
        if (tid < RG && so[tid] >= 0) {
            float mem = 0.0f;
            for (int tt = 0; tt < T_STEPS; tt++) {
                mem = __fadd_rn(__fmul_rn(mem, DECAY_F32), scur[tt][tid]);
                const float d = __fsub_rn(mem, 1.0f);
                const bool spk = d > 0.0f;
                sspk[tt][tid] = spk ? 1.0f : 0.0f;
                if (spk) mem = __fsub_rn(mem, 1.0f);
            }
        }
        __syncthreads();
#pragma unroll
        for (int q = 0; q < 4; q++) {
            const int o = so[oi * 4 + q];
            if (o >= 0)
                out[(size_t)t * NCHAIN + (size_t)b * N_DIM + o] = sspk[t][oi * 4 + q];
        }
        __syncthreads();
    }
}

// ---------------------------------------------------------------------------
// FALLBACK (R8, known-passing, ws-free).
// ---------------------------------------------------------------------------
__global__ __launch_bounds__(256)
void lif_openblas_q320(const float* __restrict__ X, const float* __restrict__ W,
                       const float* __restrict__ bias, float* __restrict__ out) {
    __shared__ float As[16][T_STEPS + 4];
    __shared__ float Ws[16][64 + 4];
    __shared__ float curbuf[T_STEPS][64 + 1];
    const int tid = threadIdx.x;
    const int o0 = blockIdx.x * 64, b0 = blockIdx.y;
    const int tm = (tid & 15) * 4, tn = (tid >> 4) * 4;
    float Csum[4][4], Pacc[4][4];
#pragma unroll
    for (int i = 0; i < 4; i++)
#pragma unroll
        for (int j = 0; j < 4; j++) { Csum[i][j] = 0.f; Pacc[i][j] = 0.f; }
    for (int c = 0; c < K_DIM / 16; c++) {
        if (c > 0 && (c % 20) == 0) {
#pragma unroll
            for (int i = 0; i < 4; i++)
#pragma unroll
                for (int j = 0; j < 4; j++) {
                    Csum[i][j] = __fadd_rn(Csum[i][j], Pacc[i][j]);
                    Pacc[i][j] = 0.f;
                }
        }
        const int k0 = c * 16;
        {
            const int t = tid >> 2, kq = (tid & 3) * 4;
            const float4 av = *(const float4*)&X[(size_t)(t * BATCH + b0) * K_DIM + k0 + kq];
            As[kq + 0][t] = av.x; As[kq + 1][t] = av.y;
            As[kq + 2][t] = av.z; As[kq + 3][t] = av.w;
            const float4 wv = *(const float4*)&W[(size_t)(o0 + t) * K_DIM + k0 + kq];
            Ws[kq + 0][t] = wv.x; Ws[kq + 1][t] = wv.y;
            Ws[kq + 2][t] = wv.z; Ws[kq + 3][t] = wv.w;
        }
        __syncthreads();
#pragma unroll
        for (int k = 0; k < 16; k++) {
            float a[4], w[4];
#pragma unroll
            for (int i = 0; i < 4; i++) a[i] = As[k][tm + i];
#pragma unroll
            for (int j = 0; j < 4; j++) w[j] = Ws[k][tn + j];
#pragma unroll
            for (int i = 0; i < 4; i++)
#pragma unroll
                for (int j = 0; j < 4; j++) Pacc[i][j] = fmaf(a[i], w[j], Pacc[i][j]);
        }
        __syncthreads();
    }
#pragma unroll
    for (int i = 0; i < 4; i++)
#pragma unroll
        for (int j = 0; j < 4; j++)
            curbuf[tm + i][tn + j] =
                __fadd_rn(__fadd_rn(Csum[i][j], Pacc[i][j]), bias[o0 + tn + j]);
    __syncthreads();
    if (tid < 64) {
        float mem = 0.0f;
#pragma unroll
        for (int t = 0; t < T_STEPS; t++) {
            mem = __fadd_rn(__fmul_rn(mem, DECAY_F32), curbuf[t][tid]);
            const float d = __fsub_rn(mem, 1.0f);
            const bool spk = d > 0.0f;
            out[(size_t)t * NCHAIN + (size_t)b0 * N_DIM + o0 + tid] = spk ? 1.0f : 0.0f;
            if (spk) mem = __fsub_rn(mem, 1.0f);
        }
    }
}

extern "C" void kernel_launch(void* const* d_in, const int* in_sizes, int n_in,
                              void* d_out, int out_size, void* d_ws, size_t ws_size,
                              hipStream_t stream) {
    const float* x = nullptr; const float* W = nullptr; const float* bias = nullptr;
    for (int i = 0; i < n_in; i++) {
        if      (in_sizes[i] == M_DIM * K_DIM) x    = (const float*)d_in[i];
        else if (in_sizes[i] == N_DIM * K_DIM) W    = (const float*)d_in[i];
        else if (in_sizes[i] == N_DIM)         bias = (const float*)d_in[i];
    }
    if (!x)    x    = (const float*)d_in[0];
    if (!W)    W    = (const float*)d_in[1];
    if (!bias) bias = (const float*)d_in[2];
    float* out = (float*)d_out;

    // workspace layout
    const size_t off_cnt = 0;                                     // 128 u32
    const size_t off_wl  = 512;                                   // 128*2048 u32
    const size_t off_Ah  = off_wl + (size_t)128 * 2048 * 4;       // 1049088
    const size_t szA     = (size_t)M_DIM * K_DIM * 2;             // 32 MiB
    const size_t szW     = (size_t)N_DIM * K_DIM * 2;             //  8 MiB
    const size_t off_Al  = off_Ah + szA;
    const size_t off_Wh  = off_Al + szA;
    const size_t off_Wl  = off_Wh + szW;
    const size_t need    = off_Wl + szW;

    if (ws_size < need) {
        dim3 grid(N_DIM / 64, BATCH);
        lif_openblas_q320<<<grid, 256, 0, stream>>>(x, W, bias, out);
        return;
    }

    char* ws = (char*)d_ws;
    unsigned int* counters = (unsigned int*)(ws + off_cnt);
    unsigned int* worklist = (unsigned int*)(ws + off_wl);
    u16* Ah = (u16*)(ws + off_Ah);
    u16* Al = (u16*)(ws + off_Al);
    u16* Wh = (u16*)(ws + off_Wh);
    u16* Wl = (u16*)(ws + off_Wl);

    zero_counters<<<1, 128, 0, stream>>>(counters);
    split_bf16<<<(M_DIM * K_DIM / 4 + N_DIM * K_DIM / 4) / 256, 256, 0, stream>>>(
        x, W, Ah, Al, Wh, Wl);
    dim3 ggrid(N_DIM / 128, M_DIM / 256);   // (16, 32)
    gemm_bf16x3p<<<ggrid, 512, 147456, stream>>>(Ah, Al, Wh, Wl, bias, out);
    lif_scan_band<<<NCHAIN / 256, 256, 0, stream>>>(out, counters, worklist);
    lif_repair2<<<128 * RJ, 256, 0, stream>>>(x, W, bias, counters, worklist, out);
}

// Round 6
// 472.249 us; speedup vs baseline: 1.1748x; 1.0197x over previous
//
#include <hip/hip_runtime.h>
#include <hip/hip_bf16.h>
#include <math.h>

// ---------------------------------------------------------------------------
// LIF layer, round 16: bf16x3 MFMA GEMM, 3-stage ring + counted vmcnt (R15)
// + REGISTER-DOUBLE-BUFFERED FRAGMENTS (ds_read next step's frags under the
// current MFMA cluster; 3-ahead staging) + fused zero+split + coalesced
// repair X-staging.
//
// R15 post-mortem: 220us / MfmaUtil 41%. Per-step model: MFMA 646cy,
// LDS reads 512cy (overlappable), measured 1576cy -> ~900cy bubbles from
// the serial {barrier -> 16 ds_read -> MFMA} chain at each step top.
// R16: frags for step kc are read during step kc-1's MFMAs. Invariants:
//   top of kc: vmcnt(6)  -> stage kc+1 landed (outstanding = kc+2's 6)
//              lgkmcnt(0)-> my reads of slot kc%3 are in registers
//              s_barrier -> both true block-wide
//   then: LOADF(next) <- slot (kc+1)%3 ; STAGE(slot kc%3, kc+3) ; 48 MFMA.
// MFMA order per acc element unchanged -> bitwise-identical C -> absmax 0.
// ---------------------------------------------------------------------------

typedef unsigned short u16;
typedef __attribute__((ext_vector_type(8))) short bf16x8;
typedef __attribute__((ext_vector_type(4))) float f32x4;

constexpr int T_STEPS = 64;
constexpr int BATCH   = 128;
constexpr int K_DIM   = 2048;
constexpr int N_DIM   = 2048;
constexpr int M_DIM   = T_STEPS * BATCH;      // 8192
constexpr int NCHAIN  = BATCH * N_DIM;        // 262144

constexpr float DECAY_F32 = (float)0.6065306597126334;
constexpr float BAND      = 5e-4f;

#define GLDS16(g, l) __builtin_amdgcn_global_load_lds(                       \
    (const __attribute__((address_space(1))) void*)(g),                      \
    (__attribute__((address_space(3))) void*)(l), 16, 0, 0)

// ---------------------------------------------------------------------------
// k2: Dekker split f32 -> bf16 hi/lo, 4 elems/thread; block 0 also zeroes
// the 128 per-b worklist counters (fused former zero_counters launch).
// ---------------------------------------------------------------------------
__global__ __launch_bounds__(256)
void split_bf16(const float* __restrict__ X, const float* __restrict__ W,
                u16* __restrict__ Ah, u16* __restrict__ Al,
                u16* __restrict__ Wh, u16* __restrict__ Wl,
                unsigned int* __restrict__ counters) {
    if (blockIdx.x == 0 && threadIdx.x < 128) counters[threadIdx.x] = 0u;

    constexpr int NA4 = (M_DIM * K_DIM) / 4;
    constexpr int NW4 = (N_DIM * K_DIM) / 4;
    const int i = blockIdx.x * 256 + threadIdx.x;
    const float* src; u16* dh; u16* dl; int base;
    if (i < NA4)            { src = X; dh = Ah; dl = Al; base = i; }
    else if (i < NA4 + NW4) { src = W; dh = Wh; dl = Wl; base = i - NA4; }
    else return;

    const float4 v = *(const float4*)(src + (size_t)base * 4);
    const float f[4] = {v.x, v.y, v.z, v.w};
    unsigned int hp[2], lp[2];
#pragma unroll
    for (int q = 0; q < 4; q += 2) {
        u16 hh[2], ll[2];
#pragma unroll
        for (int e = 0; e < 2; e++) {
            __hip_bfloat16 hb = __float2bfloat16(f[q + e]);
            const float hf = __bfloat162float(hb);
            __hip_bfloat16 lb = __float2bfloat16(f[q + e] - hf);
            hh[e] = *(u16*)&hb;
            ll[e] = *(u16*)&lb;
        }
        hp[q >> 1] = (unsigned int)hh[0] | ((unsigned int)hh[1] << 16);
        lp[q >> 1] = (unsigned int)ll[0] | ((unsigned int)ll[1] << 16);
    }
    *(uint2*)(dh + (size_t)base * 4) = make_uint2(hp[0], hp[1]);
    *(uint2*)(dl + (size_t)base * 4) = make_uint2(lp[0], lp[1]);
}

// ---------------------------------------------------------------------------
// k3: bf16x3 MFMA GEMM (hh + hl + lh), 256x128 tile, 8 waves (4m x 2n),
// BK=32, 3-stage LDS ring, counted vmcnt, register-double-buffered frags.
// ---------------------------------------------------------------------------
__global__ __launch_bounds__(512, 2)
void gemm_bf16x3q(const u16* __restrict__ Ah, const u16* __restrict__ Al,
                  const u16* __restrict__ Bh, const u16* __restrict__ Bl,
                  const float* __restrict__ bias, float* __restrict__ C) {
    extern __shared__ __align__(16) u16 smem[];
    u16* const sAh = smem;                          // [3][8192]
    u16* const sAl = smem + 3 * 8192;               // [3][8192]
    u16* const sBh = smem + 6 * 8192;               // [3][4096]
    u16* const sBl = smem + 6 * 8192 + 3 * 4096;    // [3][4096]

    const int tid  = threadIdx.x;
    const int m0   = blockIdx.y * 256;
    const int n0   = blockIdx.x * 128;
    const int lane = tid & 63;
    const int wave = tid >> 6;     // 0..7
    const int wm   = wave >> 1;    // 0..3 (64-row slab)
    const int wn   = wave & 1;     // 0..1 (64-col slab)

    const int cA0 = tid, cA1 = tid + 512, cB0 = tid;
#define OFFA(c) ((size_t)(m0 + ((c) >> 6) * 16 + ((c) & 15)) * K_DIM + (((c) >> 4) & 3) * 8)
#define OFFB(c) ((size_t)(n0 + ((c) >> 6) * 16 + ((c) & 15)) * K_DIM + (((c) >> 4) & 3) * 8)
    const size_t a0 = OFFA(cA0), a1 = OFFA(cA1), b0 = OFFB(cB0);
#undef OFFA
#undef OFFB

    // wave-uniform LDS dest offsets (u16) within a stage; HW adds lane*16B.
    const int lA0 = wave * 512;
    const int lA1 = 4096 + wave * 512;
    const int lB0 = wave * 512;

    f32x4 acc[4][4];
#pragma unroll
    for (int i = 0; i < 4; i++)
#pragma unroll
        for (int j = 0; j < 4; j++) acc[i][j] = (f32x4){0.f, 0.f, 0.f, 0.f};

    bf16x8 fahA[4], falA[4], fbhA[4], fblA[4];
    bf16x8 fahB[4], falB[4], fbhB[4], fblB[4];

#define STAGE(s, kc) do {                                                    \
        const int kn_ = (kc) * 32;                                           \
        const int sA_ = (s) * 8192, sB_ = (s) * 4096;                        \
        GLDS16(Ah + a0 + kn_, sAh + sA_ + lA0);                              \
        GLDS16(Ah + a1 + kn_, sAh + sA_ + lA1);                              \
        GLDS16(Al + a0 + kn_, sAl + sA_ + lA0);                              \
        GLDS16(Al + a1 + kn_, sAl + sA_ + lA1);                              \
        GLDS16(Bh + b0 + kn_, sBh + sB_ + lB0);                              \
        GLDS16(Bl + b0 + kn_, sBl + sB_ + lB0);                              \
    } while (0)

#define LOADF(SET, s) do {                                                   \
        const int sA_ = (s) * 8192, sB_ = (s) * 4096;                        \
        _Pragma("unroll")                                                    \
        for (int ti = 0; ti < 4; ti++) {                                     \
            const int ta = wm * 4 + ti;                                      \
            fah##SET[ti] = *(const bf16x8*)&sAh[sA_ + (ta * 64 + lane) * 8]; \
            fal##SET[ti] = *(const bf16x8*)&sAl[sA_ + (ta * 64 + lane) * 8]; \
        }                                                                    \
        _Pragma("unroll")                                                    \
        for (int tj = 0; tj < 4; tj++) {                                     \
            const int tb = wn * 4 + tj;                                      \
            fbh##SET[tj] = *(const bf16x8*)&sBh[sB_ + (tb * 64 + lane) * 8]; \
            fbl##SET[tj] = *(const bf16x8*)&sBl[sB_ + (tb * 64 + lane) * 8]; \
        }                                                                    \
    } while (0)

#define COMPUTE(SET) do {                                                    \
        __builtin_amdgcn_s_setprio(1);                                       \
        _Pragma("unroll")                                                    \
        for (int ti = 0; ti < 4; ti++)                                       \
        _Pragma("unroll")                                                    \
        for (int tj = 0; tj < 4; tj++) {                                     \
            acc[ti][tj] = __builtin_amdgcn_mfma_f32_16x16x32_bf16(           \
                fah##SET[ti], fbh##SET[tj], acc[ti][tj], 0, 0, 0);           \
            acc[ti][tj] = __builtin_amdgcn_mfma_f32_16x16x32_bf16(           \
                fah##SET[ti], fbl##SET[tj], acc[ti][tj], 0, 0, 0);           \
            acc[ti][tj] = __builtin_amdgcn_mfma_f32_16x16x32_bf16(           \
                fal##SET[ti], fbh##SET[tj], acc[ti][tj], 0, 0, 0);           \
        }                                                                    \
        __builtin_amdgcn_s_setprio(0);                                       \
    } while (0)

#define WAITSYNC(vm) do {                                                    \
        asm volatile("s_waitcnt vmcnt(" #vm ") lgkmcnt(0)" ::: "memory");    \
        __builtin_amdgcn_sched_barrier(0);                                   \
        __builtin_amdgcn_s_barrier();                                        \
        __builtin_amdgcn_sched_barrier(0);                                   \
    } while (0)

    // prologue: 3 stages in flight (18 loads)
    STAGE(0, 0);
    STAGE(1, 1);
    STAGE(2, 2);
    WAITSYNC(12);          // stage 0 landed
    LOADF(A, 0);           // frags for step 0

    int s1 = 1, sW = 0;    // s1 = (kc+1)%3 read-slot, sW = kc%3 write-slot
    for (int kc = 0; kc < 62; kc += 2) {
        // even step kc: consume A, prefetch B <- stage kc+1, stage kc+3
        WAITSYNC(6);
        LOADF(B, s1);
        if (kc + 3 < 64) STAGE(sW, kc + 3);
        COMPUTE(A);
        s1 = (s1 == 2) ? 0 : s1 + 1;
        sW = (sW == 2) ? 0 : sW + 1;
        // odd step kc+1: consume B, prefetch A <- stage kc+2, stage kc+4
        WAITSYNC(6);
        LOADF(A, s1);
        if (kc + 4 < 64) STAGE(sW, kc + 4);
        COMPUTE(B);
        s1 = (s1 == 2) ? 0 : s1 + 1;
        sW = (sW == 2) ? 0 : sW + 1;
    }
    // peeled kc=62: stage 63 is the only one in flight -> vmcnt(0)
    WAITSYNC(0);
    LOADF(B, s1);          // s1 == 63 % 3 == 0
    COMPUTE(A);            // stage-62 frags (loaded at step 61)
    // peeled kc=63
    COMPUTE(B);

#undef WAITSYNC
#undef COMPUTE
#undef LOADF
#undef STAGE

#pragma unroll
    for (int tj = 0; tj < 4; tj++) {
        const int n  = n0 + wn * 64 + tj * 16 + (lane & 15);
        const float bv = bias[n];
#pragma unroll
        for (int ti = 0; ti < 4; ti++) {
            const int mbase = m0 + wm * 64 + ti * 16 + (lane >> 4) * 4;
#pragma unroll
            for (int r = 0; r < 4; r++)
                C[(size_t)(mbase + r) * N_DIM + n] = acc[ti][tj][r] + bv;
        }
    }
}

// ---------------------------------------------------------------------------
// k4: banded scan; flagged chains go to per-b worklists.
// ---------------------------------------------------------------------------
__global__ __launch_bounds__(256)
void lif_scan_band(float* __restrict__ buf, unsigned int* __restrict__ counters,
                   unsigned int* __restrict__ worklist) {
    const int idx = blockIdx.x * 256 + threadIdx.x;   // chain = b*2048 + o
    float mem = 0.0f;
    bool flag = false;
#pragma unroll
    for (int t = 0; t < T_STEPS; t++) {
        const size_t off = (size_t)t * NCHAIN + idx;
        mem = __fadd_rn(__fmul_rn(mem, DECAY_F32), buf[off]);
        const float d = __fsub_rn(mem, 1.0f);
        const bool spk = d > 0.0f;
        if (fabsf(d) < BAND) flag = true;
        buf[off] = spk ? 1.0f : 0.0f;
        if (spk) mem = __fsub_rn(mem, 1.0f);
    }
    if (flag) {
        const int b = idx >> 11, o = idx & 2047;
        const unsigned int p = atomicAdd(&counters[b], 1u);
        worklist[b * 2048 + p] = (unsigned int)o;
    }
}

// ---------------------------------------------------------------------------
// k5: b-grouped exact repair. X-staging remapped for coalescing: 4 adjacent
// lanes cover 256 B contiguous per row (was 64 lanes x 16 B at 8 KB stride).
// sX contents identical to R15 -> numerics unchanged.
// ---------------------------------------------------------------------------
#define RG 16    // chains per group
#define RJ 4     // block-strides per b
#define BKR 64   // k-chunk (320 = 5*64: panel boundaries land on chunk edges)

__global__ __launch_bounds__(256)
void lif_repair2(const float* __restrict__ X, const float* __restrict__ W,
                 const float* __restrict__ bias,
                 const unsigned int* __restrict__ counters,
                 const unsigned int* __restrict__ worklist,
                 float* __restrict__ out) {
    __shared__ float sX[BKR][T_STEPS + 1];      // [k][t] 16.25 KiB
    __shared__ float sW[RG][BKR + 1];           // [o][k]  4.06 KiB
    __shared__ float scur[T_STEPS][RG + 1];
    __shared__ float sspk[T_STEPS][RG + 1];
    __shared__ int   so[RG];

    const int b = blockIdx.x / RJ;
    const int j = blockIdx.x % RJ;
    const unsigned int n_b = counters[b];
    if (n_b == 0) return;
    const int ngroups = (int)(n_b + RG - 1) / RG;

    const int tid = threadIdx.x;
    const int t   = tid & 63;
    const int oi  = tid >> 6;          // 0..3, owns o-slots 4*oi .. 4*oi+3

    for (int g = j; g < ngroups; g += RJ) {
        if (tid < RG) {
            const int slot = g * RG + tid;
            so[tid] = (slot < (int)n_b) ? (int)worklist[b * 2048 + slot] : -1;
        }
        __syncthreads();

        float Csum[4] = {0.f, 0.f, 0.f, 0.f};
        float P[4]    = {0.f, 0.f, 0.f, 0.f};

        for (int c = 0; c < K_DIM / BKR; c++) {
            if (c > 0 && (c % 5) == 0) {       // k = 320*j panel boundary
#pragma unroll
                for (int q = 0; q < 4; q++) {
                    Csum[q] = __fadd_rn(Csum[q], P[q]);
                    P[q] = 0.f;
                }
            }
            const int k0 = c * BKR;
            // stage X chunk: 64 t x 64 k; lanes 4i..4i+3 read row i's 256 B
            {
                const int ts = tid >> 2;            // 0..63 row
                const int kq = (tid & 3) * 16;      // 0..48 col quarter
                const float* src = &X[(size_t)(ts * BATCH + b) * K_DIM + k0 + kq];
#pragma unroll
                for (int q = 0; q < 4; q++) {
                    const float4 v = *(const float4*)(src + q * 4);
                    sX[kq + q * 4 + 0][ts] = v.x;
                    sX[kq + q * 4 + 1][ts] = v.y;
                    sX[kq + q * 4 + 2][ts] = v.z;
                    sX[kq + q * 4 + 3][ts] = v.w;
                }
            }
            // stage W chunk: 16 o x 64 k, 1 float4 per thread
            {
                const int wo  = tid >> 4;          // 0..15
                const int wkq = (tid & 15) * 4;    // 0..60
                const int o   = so[wo];
                float4 v = {0.f, 0.f, 0.f, 0.f};
                if (o >= 0) v = *(const float4*)&W[(size_t)o * K_DIM + k0 + wkq];
                sW[wo][wkq + 0] = v.x; sW[wo][wkq + 1] = v.y;
                sW[wo][wkq + 2] = v.z; sW[wo][wkq + 3] = v.w;
            }
            __syncthreads();
            // exact sequential-k FMA, 4 independent chains (ILP)
#pragma unroll 8
            for (int k = 0; k < BKR; k++) {
                const float xv = sX[k][t];
#pragma unroll
                for (int q = 0; q < 4; q++)
                    P[q] = fmaf(xv, sW[oi * 4 + q][k], P[q]);
            }
            __syncthreads();
        }
#pragma unroll
        for (int q = 0; q < 4; q++) {
            Csum[q] = __fadd_rn(Csum[q], P[q]);    // final 128-elem panel
            const int o = so[oi * 4 + q];
            scur[t][oi * 4 + q] = (o >= 0) ? __fadd_rn(Csum[q], bias[o]) : 0.f;
        }
        __syncthreads();
        if (tid < RG && so[tid] >= 0) {
            float mem = 0.0f;
            for (int tt = 0; tt < T_STEPS; tt++) {
                mem = __fadd_rn(__fmul_rn(mem, DECAY_F32), scur[tt][tid]);
                const float d = __fsub_rn(mem, 1.0f);
                const bool spk = d > 0.0f;
                sspk[tt][tid] = spk ? 1.0f : 0.0f;
                if (spk) mem = __fsub_rn(mem, 1.0f);
            }
        }
        __syncthreads();
#pragma unroll
        for (int q = 0; q < 4; q++) {
            const int o = so[oi * 4 + q];
            if (o >= 0)
                out[(size_t)t * NCHAIN + (size_t)b * N_DIM + o] = sspk[t][oi * 4 + q];
        }
        __syncthreads();
    }
}

// ---------------------------------------------------------------------------
// FALLBACK (R8, known-passing, ws-free).
// ---------------------------------------------------------------------------
__global__ __launch_bounds__(256)
void lif_openblas_q320(const float* __restrict__ X, const float* __restrict__ W,
                       const float* __restrict__ bias, float* __restrict__ out) {
    __shared__ float As[16][T_STEPS + 4];
    __shared__ float Ws[16][64 + 4];
    __shared__ float curbuf[T_STEPS][64 + 1];
    const int tid = threadIdx.x;
    const int o0 = blockIdx.x * 64, b0 = blockIdx.y;
    const int tm = (tid & 15) * 4, tn = (tid >> 4) * 4;
    float Csum[4][4], Pacc[4][4];
#pragma unroll
    for (int i = 0; i < 4; i++)
#pragma unroll
        for (int j = 0; j < 4; j++) { Csum[i][j] = 0.f; Pacc[i][j] = 0.f; }
    for (int c = 0; c < K_DIM / 16; c++) {
        if (c > 0 && (c % 20) == 0) {
#pragma unroll
            for (int i = 0; i < 4; i++)
#pragma unroll
                for (int j = 0; j < 4; j++) {
                    Csum[i][j] = __fadd_rn(Csum[i][j], Pacc[i][j]);
                    Pacc[i][j] = 0.f;
                }
        }
        const int k0 = c * 16;
        {
            const int t = tid >> 2, kq = (tid & 3) * 4;
            const float4 av = *(const float4*)&X[(size_t)(t * BATCH + b0) * K_DIM + k0 + kq];
            As[kq + 0][t] = av.x; As[kq + 1][t] = av.y;
            As[kq + 2][t] = av.z; As[kq + 3][t] = av.w;
            const float4 wv = *(const float4*)&W[(size_t)(o0 + t) * K_DIM + k0 + kq];
            Ws[kq + 0][t] = wv.x; Ws[kq + 1][t] = wv.y;
            Ws[kq + 2][t] = wv.z; Ws[kq + 3][t] = wv.w;
        }
        __syncthreads();
#pragma unroll
        for (int k = 0; k < 16; k++) {
            float a[4], w[4];
#pragma unroll
            for (int i = 0; i < 4; i++) a[i] = As[k][tm + i];
#pragma unroll
            for (int j = 0; j < 4; j++) w[j] = Ws[k][tn + j];
#pragma unroll
            for (int i = 0; i < 4; i++)
#pragma unroll
                for (int j = 0; j < 4; j++) Pacc[i][j] = fmaf(a[i], w[j], Pacc[i][j]);
        }
        __syncthreads();
    }
#pragma unroll
    for (int i = 0; i < 4; i++)
#pragma unroll
        for (int j = 0; j < 4; j++)
            curbuf[tm + i][tn + j] =
                __fadd_rn(__fadd_rn(Csum[i][j], Pacc[i][j]), bias[o0 + tn + j]);
    __syncthreads();
    if (tid < 64) {
        float mem = 0.0f;
#pragma unroll
        for (int t = 0; t < T_STEPS; t++) {
            mem = __fadd_rn(__fmul_rn(mem, DECAY_F32), curbuf[t][tid]);
            const float d = __fsub_rn(mem, 1.0f);
            const bool spk = d > 0.0f;
            out[(size_t)t * NCHAIN + (size_t)b0 * N_DIM + o0 + tid] = spk ? 1.0f : 0.0f;
            if (spk) mem = __fsub_rn(mem, 1.0f);
        }
    }
}

extern "C" void kernel_launch(void* const* d_in, const int* in_sizes, int n_in,
                              void* d_out, int out_size, void* d_ws, size_t ws_size,
                              hipStream_t stream) {
    const float* x = nullptr; const float* W = nullptr; const float* bias = nullptr;
    for (int i = 0; i < n_in; i++) {
        if      (in_sizes[i] == M_DIM * K_DIM) x    = (const float*)d_in[i];
        else if (in_sizes[i] == N_DIM * K_DIM) W    = (const float*)d_in[i];
        else if (in_sizes[i] == N_DIM)         bias = (const float*)d_in[i];
    }
    if (!x)    x    = (const float*)d_in[0];
    if (!W)    W    = (const float*)d_in[1];
    if (!bias) bias = (const float*)d_in[2];
    float* out = (float*)d_out;

    // workspace layout
    const size_t off_cnt = 0;                                     // 128 u32
    const size_t off_wl  = 512;                                   // 128*2048 u32
    const size_t off_Ah  = off_wl + (size_t)128 * 2048 * 4;       // 1049088
    const size_t szA     = (size_t)M_DIM * K_DIM * 2;             // 32 MiB
    const size_t szW     = (size_t)N_DIM * K_DIM * 2;             //  8 MiB
    const size_t off_Al  = off_Ah + szA;
    const size_t off_Wh  = off_Al + szA;
    const size_t off_Wl  = off_Wh + szW;
    const size_t need    = off_Wl + szW;

    if (ws_size < need) {
        dim3 grid(N_DIM / 64, BATCH);
        lif_openblas_q320<<<grid, 256, 0, stream>>>(x, W, bias, out);
        return;
    }

    char* ws = (char*)d_ws;
    unsigned int* counters = (unsigned int*)(ws + off_cnt);
    unsigned int* worklist = (unsigned int*)(ws + off_wl);
    u16* Ah = (u16*)(ws + off_Ah);
    u16* Al = (u16*)(ws + off_Al);
    u16* Wh = (u16*)(ws + off_Wh);
    u16* Wl = (u16*)(ws + off_Wl);

    split_bf16<<<(M_DIM * K_DIM / 4 + N_DIM * K_DIM / 4) / 256, 256, 0, stream>>>(
        x, W, Ah, Al, Wh, Wl, counters);
    dim3 ggrid(N_DIM / 128, M_DIM / 256);   // (16, 32)
    gemm_bf16x3q<<<ggrid, 512, 147456, stream>>>(Ah, Al, Wh, Wl, bias, out);
    lif_scan_band<<<NCHAIN / 256, 256, 0, stream>>>(out, counters, worklist);
    lif_repair2<<<128 * RJ, 256, 0, stream>>>(x, W, bias, counters, worklist, out);
}